// Round 1
// baseline (393.300 us; speedup 1.0000x reference)
//
#include <hip/hip_runtime.h>
#include <cstdint>

#define IN_DIM 45
#define HDIM 128
#define DDIM 256
#define ROWS 64            // rows per block
#define NBLK 4096          // 262144 / ROWS

typedef unsigned short u16;
typedef __attribute__((ext_vector_type(8))) short v8s;     // 8 x bf16 fragment
typedef __attribute__((ext_vector_type(4))) float f32x4;   // MFMA accumulator

__device__ __forceinline__ u16 f2bf(float x){
  uint32_t u = __float_as_uint(x);
  u += 0x7FFFu + ((u >> 16) & 1u);      // round-to-nearest-even
  return (u16)(u >> 16);
}

__device__ __forceinline__ void g2l16(const void* g, void* l){
  __builtin_amdgcn_global_load_lds(
      (const __attribute__((address_space(1))) unsigned int*)g,
      (__attribute__((address_space(3))) unsigned int*)l, 16, 0, 0);
}

// d_ws layout: [0,16384): w1s bf16 [n=128][k=64] (k zero-padded 45..63), granule-swizzled
//              [16384,16384+65536): w2s bf16 [n=256][k=128], granule-swizzled
// granule = 16B (8 bf16); in-row granule g stored at g' = g ^ (n & (G-1)) to kill
// LDS bank conflicts on B-fragment ds_read_b128 (row strides are multiples of 32 banks).
__global__ void prep_kernel(const float* __restrict__ w1, const float* __restrict__ w2,
                            u16* __restrict__ w1s, u16* __restrict__ w2s){
  int idx = blockIdx.x*256 + threadIdx.x;
  if (idx < 128*64){
    int n = idx >> 6, k = idx & 63;
    int gp = (k >> 3) ^ (n & 7);                 // 8 granules/row
    float v = (k < IN_DIM) ? w1[k*HDIM + n] : 0.f;
    w1s[(n << 6) | (gp << 3) | (k & 7)] = f2bf(v);
  } else if (idx < 128*64 + 256*128){
    int t = idx - 128*64;
    int n = t >> 7, k = t & 127;
    int gp = ((k >> 3) ^ (n & 15));              // 16 granules/row
    w2s[(n << 7) | (gp << 3) | (k & 7)] = f2bf(w2[k*DDIM + n]);
  }
}

// LDS map (43008 B total -> 3 blocks/CU):
//   [0,16384)      sw : w1T (phases A-C) then w2 quarters (phase D), streamed
//   [16384,25600)  sx : x bf16 [64][72]  (stride 72 -> 2-way bank alias = free)
//   [25600,43008)  sh : hidden bf16 [64][136]; pose fp32 tile overlays here in A/B
__global__ __launch_bounds__(256, 2)
void posemlp_kernel(const float* __restrict__ pose,
                    const float* __restrict__ ln1g, const float* __restrict__ ln1b,
                    const float* __restrict__ b1v,  const float* __restrict__ b2v,
                    const float* __restrict__ ln2g, const float* __restrict__ ln2b,
                    const u16* __restrict__ w1s, const u16* __restrict__ w2s,
                    float* __restrict__ out)
{
  __shared__ __align__(16) unsigned char smem[43008];
  u16*  sw = (u16*)smem;
  u16*  sx = (u16*)(smem + 16384);
  u16*  sh = (u16*)(smem + 25600);
  float* posel = (float*)(smem + 25600);

  const int tid = threadIdx.x;
  const int blk = blockIdx.x;

  // ---- phase A: async-stage pose tile (11520 B) + w1T (16384 B)
  {
    const char* psrc = (const char*)pose + (size_t)blk * (ROWS*IN_DIM*4);
    #pragma unroll
    for (int j = 0; j < 3; ++j){
      int i = j*256 + tid;
      if (i < 720) g2l16(psrc + (size_t)i*16, smem + 25600 + i*16);
    }
    const char* wsrc = (const char*)w1s;
    #pragma unroll
    for (int j = 0; j < 4; ++j){
      int i = j*256 + tid;
      g2l16(wsrc + (size_t)i*16, smem + i*16);
    }
  }
  __syncthreads();   // drains vmcnt -> LDS valid

  // ---- phase B: LN1 (4 lanes per row) -> bf16 x, K padded to 64 with zeros
  {
    int row = tid >> 2, p = tid & 3;
    const float* pr = posel + row*IN_DIM;
    float sum = 0.f, sq = 0.f;
    for (int k = p; k < IN_DIM; k += 4){ float v = pr[k]; sum += v; sq += v*v; }
    sum += __shfl_xor(sum, 1); sum += __shfl_xor(sum, 2);
    sq  += __shfl_xor(sq, 1);  sq  += __shfl_xor(sq, 2);
    float mu = sum * (1.f/IN_DIM);
    float rs = rsqrtf(sq * (1.f/IN_DIM) - mu*mu + 1e-5f);
    u16* xr = sx + row*72;
    for (int k = p; k < IN_DIM; k += 4){
      float v = (pr[k] - mu) * rs * ln1g[k] + ln1b[k];
      xr[k] = f2bf(v);
    }
    for (int k = IN_DIM + p; k < 64; k += 4) xr[k] = 0;
  }
  __syncthreads();

  const int lane = tid & 63, wv = tid >> 6;
  const int col = lane & 15, quad = lane >> 4;

  // ---- phase C: GEMM1  (wave m-tile = rows 16*wv..+16, N=128, K=64)
  f32x4 acc1[8];
  #pragma unroll
  for (int i = 0; i < 8; ++i) acc1[i] = (f32x4){0.f,0.f,0.f,0.f};
  {
    const u16* xa = sx + (16*wv + col)*72;   // A[m=lane&15][k=quad*8+j]
    #pragma unroll
    for (int ks = 0; ks < 2; ++ks){
      v8s a = *(const v8s*)(xa + ks*32 + quad*8);
      #pragma unroll
      for (int nt = 0; nt < 8; ++nt){
        int n = nt*16 + col;
        int gp = (ks*4 + quad) ^ (n & 7);
        v8s b = *(const v8s*)(sw + n*64 + gp*8);
        acc1[nt] = __builtin_amdgcn_mfma_f32_16x16x32_bf16(a, b, acc1[nt], 0, 0, 0);
      }
    }
  }
  // bias + exact GELU -> hidden bf16 (overwrites pose overlay; pose reads all done)
  #pragma unroll
  for (int nt = 0; nt < 8; ++nt){
    int n = nt*16 + col;
    float bias = b1v[n];
    #pragma unroll
    for (int r = 0; r < 4; ++r){
      float v = acc1[nt][r] + bias;                       // C: row=quad*4+r, col=n
      v = 0.5f * v * (1.f + erff(v * 0.70710678118654752f));
      sh[(16*wv + quad*4 + r)*136 + n] = f2bf(v);
    }
  }
  __syncthreads();   // GEMM1 B-reads done (sw free) + hidden complete

  // A-fragments for GEMM2, reused across all four w2 quarters
  v8s a2[4];
  {
    const u16* ha = sh + (16*wv + col)*136;
    #pragma unroll
    for (int ks = 0; ks < 4; ++ks) a2[ks] = *(const v8s*)(ha + ks*32 + quad*8);
  }

  // ---- phase D: GEMM2, w2 streamed through sw in 4 N-quarters of 64
  f32x4 acc2[16];
  #pragma unroll
  for (int i = 0; i < 16; ++i) acc2[i] = (f32x4){0.f,0.f,0.f,0.f};
  const char* w2b = (const char*)w2s;
  #pragma unroll
  for (int hq = 0; hq < 4; ++hq){
    #pragma unroll
    for (int j = 0; j < 4; ++j){
      int i = j*256 + tid;
      g2l16(w2b + (size_t)hq*16384 + (size_t)i*16, smem + i*16);
    }
    __syncthreads();                     // quarter staged
    #pragma unroll
    for (int ntl = 0; ntl < 4; ++ntl){
      int nq = ntl*16 + col;             // row within quarter
      #pragma unroll
      for (int ks = 0; ks < 4; ++ks){
        int gp = (ks*4 + quad) ^ (nq & 15);
        v8s b = *(const v8s*)(sw + nq*128 + gp*8);
        acc2[hq*4 + ntl] = __builtin_amdgcn_mfma_f32_16x16x32_bf16(a2[ks], b, acc2[hq*4 + ntl], 0, 0, 0);
      }
    }
    __syncthreads();                     // all reads done before next overwrite
  }

  // ---- phase E: +b2, LN2 over 256, store fp32
  float sum[4] = {0,0,0,0}, sq[4] = {0,0,0,0};
  #pragma unroll
  for (int i = 0; i < 16; ++i){
    float bb = b2v[i*16 + col];
    #pragma unroll
    for (int r = 0; r < 4; ++r){
      float v = acc2[i][r] + bb;
      acc2[i][r] = v;
      sum[r] += v; sq[r] += v*v;
    }
  }
  #pragma unroll
  for (int m = 1; m <= 8; m <<= 1){      // butterfly within 16-lane quad group
    #pragma unroll
    for (int r = 0; r < 4; ++r){
      sum[r] += __shfl_xor(sum[r], m);
      sq[r]  += __shfl_xor(sq[r], m);
    }
  }
  float mu[4], rs[4];
  #pragma unroll
  for (int r = 0; r < 4; ++r){
    mu[r] = sum[r] * (1.f/DDIM);
    rs[r] = rsqrtf(sq[r] * (1.f/DDIM) - mu[r]*mu[r] + 1e-5f);
  }
  const int rbase = blk*ROWS + 16*wv + quad*4;
  #pragma unroll
  for (int r = 0; r < 4; ++r){
    #pragma unroll
    for (int i = 0; i < 16; ++i){
      int n = i*16 + col;
      out[(size_t)(rbase + r)*DDIM + n] =
          (acc2[i][r] - mu[r]) * rs[r] * ln2g[n] + ln2b[n];
    }
  }
}

extern "C" void kernel_launch(void* const* d_in, const int* in_sizes, int n_in,
                              void* d_out, int out_size, void* d_ws, size_t ws_size,
                              hipStream_t stream){
  const float* pose = (const float*)d_in[0];
  const float* ln1g = (const float*)d_in[1];
  const float* ln1b = (const float*)d_in[2];
  const float* w1   = (const float*)d_in[3];
  const float* b1   = (const float*)d_in[4];
  const float* w2   = (const float*)d_in[5];
  const float* b2   = (const float*)d_in[6];
  const float* ln2g = (const float*)d_in[7];
  const float* ln2b = (const float*)d_in[8];
  u16* w1s = (u16*)d_ws;
  u16* w2s = (u16*)((char*)d_ws + 16384);   // needs 81920 B of d_ws
  prep_kernel<<<160, 256, 0, stream>>>(w1, w2, w1s, w2s);
  posemlp_kernel<<<NBLK, 256, 0, stream>>>(pose, ln1g, ln1b, b1, b2, ln2g, ln2b,
                                           w1s, w2s, (float*)d_out);
}